// Round 1
// baseline (237.262 us; speedup 1.0000x reference)
//
#include <hip/hip_runtime.h>

typedef _Float16 f16;
typedef _Float16 f16x8 __attribute__((ext_vector_type(8)));
typedef _Float16 f16x4 __attribute__((ext_vector_type(4)));
typedef float f32x4 __attribute__((ext_vector_type(4)));

#define B_TOT 128
#define T_LEN 512
#define D_DIM 256
#define H_DIM 512

// ---------------- helpers ----------------
__device__ __forceinline__ void gload_lds16(const void* g, void* l) {
  __builtin_amdgcn_global_load_lds(
      (const __attribute__((address_space(1))) void*)g,
      (__attribute__((address_space(3))) void*)l, 16, 0, 0);
}

__device__ __forceinline__ float fast_tanh(float x) {
  float e = __expf(2.0f * x);
  return 1.0f - 2.0f / (e + 1.0f);
}
__device__ __forceinline__ float fast_sigmoid(float x) {
  return 1.0f / (1.0f + __expf(-x));
}

// ---------------- kernel 1: weight convert + transpose ----------------
// W[k][n] f32 (256x512) -> Wt[n][k] f16 (512x256), 3 weights
__global__ void __launch_bounds__(256) cvt_w(const float* __restrict__ Wr,
                                             const float* __restrict__ Wz,
                                             const float* __restrict__ Wh,
                                             f16* __restrict__ Wt) {
  int idx = blockIdx.x * 256 + threadIdx.x;      // < 3*131072
  int w = idx >> 17;
  int rem = idx & 131071;
  int n = rem >> 8;        // 0..511
  int k = rem & 255;       // 0..255
  const float* W = (w == 0) ? Wr : ((w == 1) ? Wz : Wh);
  Wt[(size_t)w * 131072 + n * 256 + k] = (f16)W[k * 512 + n];
}

// ---------------- kernel 2: x convert f32 -> f16 ----------------
__global__ void __launch_bounds__(256) cvt_x(const float4* __restrict__ in,
                                             f16x4* __restrict__ out) {
  int idx = blockIdx.x * 256 + threadIdx.x;
  float4 v = in[idx];
  f16x4 o;
  o[0] = (f16)v.x; o[1] = (f16)v.y; o[2] = (f16)v.z; o[3] = (f16)v.w;
  out[idx] = o;
}

// ---------------- kernel 3: fused 3-weight GEMM ----------------
// X [M][256] f16, Wt [512][256] f16 (pre-transposed), P [M][512] f16
// tile: BM=128 x (BN=64 per weight), BK=32; 256 threads = 4 waves (2x2)
#define BM 128
#define BN 64
#define BK 32

__global__ void __launch_bounds__(256) brc_gemm3(
    const f16* __restrict__ X,
    const f16* __restrict__ Wr, const f16* __restrict__ Wz, const f16* __restrict__ Wh,
    f16* __restrict__ Pr, f16* __restrict__ Pz, f16* __restrict__ Ph,
    int Mtiles) {
  __shared__ f16 lds[BM * BK + 3 * BN * BK];   // 4096 + 6144 halfs = 20 KiB
  const int tid = threadIdx.x;
  const int wid = tid >> 6, lane = tid & 63;
  const int bid = blockIdx.x;
  const int mt = bid % Mtiles, nt = bid / Mtiles;
  const int m0 = mt * BM, n0 = nt * BN;
  const int wr = wid >> 1, wc = wid & 1;   // 2x2 wave grid: wave tile 64x32

  f32x4 acc[3][4][2] = {};

  for (int kt = 0; kt < 8; ++kt) {
    const int k0 = kt * BK;
    // ---- stage A: 128x32 halfs = 8192B, 2 x 16B per thread ----
#pragma unroll
    for (int c = 0; c < 2; ++c) {
      int o = c * 4096 + wid * 1024 + lane * 16;            // byte offset in tile
      const char* g = (const char*)X + ((size_t)(m0 + (o >> 6))) * 512 + k0 * 2 + (o & 63);
      char* l = (char*)lds + c * 4096 + wid * 1024;         // wave-uniform dest
      gload_lds16(g, l);
    }
    // ---- stage B: 3 x (64x32 halfs = 4096B), 1 x 16B per thread per weight ----
    {
      int o = wid * 1024 + lane * 16;
      size_t goff = ((size_t)(n0 + (o >> 6))) * 512 + k0 * 2 + (o & 63);
      char* l = (char*)lds + 8192 + wid * 1024;             // wave-uniform dest
      gload_lds16((const char*)Wr + goff, l);
      gload_lds16((const char*)Wz + goff, l + 4096);
      gload_lds16((const char*)Wh + goff, l + 8192);
    }
    __syncthreads();

    f16x8 a[4], b[3][2];
#pragma unroll
    for (int mi = 0; mi < 4; ++mi)
      a[mi] = *(const f16x8*)&lds[(wr * 64 + mi * 16 + (lane & 15)) * BK + (lane >> 4) * 8];
#pragma unroll
    for (int w = 0; w < 3; ++w)
#pragma unroll
      for (int ni = 0; ni < 2; ++ni)
        b[w][ni] = *(const f16x8*)&lds[BM * BK + w * (BN * BK) +
                                       (wc * 32 + ni * 16 + (lane & 15)) * BK + (lane >> 4) * 8];
#pragma unroll
    for (int w = 0; w < 3; ++w)
#pragma unroll
      for (int mi = 0; mi < 4; ++mi)
#pragma unroll
        for (int ni = 0; ni < 2; ++ni)
          acc[w][mi][ni] = __builtin_amdgcn_mfma_f32_16x16x32_f16(
              a[mi], b[w][ni], acc[w][mi][ni], 0, 0, 0);
    __syncthreads();
  }

  // ---- epilogue: C/D layout col = lane&15, row = (lane>>4)*4 + r ----
  const int col = lane & 15;
  const int rbase = (lane >> 4) * 4;
#pragma unroll
  for (int w = 0; w < 3; ++w) {
    f16* P = (w == 0) ? Pr : ((w == 1) ? Pz : Ph);
#pragma unroll
    for (int mi = 0; mi < 4; ++mi)
#pragma unroll
      for (int ni = 0; ni < 2; ++ni) {
        size_t base = ((size_t)(m0 + wr * 64 + mi * 16 + rbase)) * 512 +
                      (n0 + wc * 32 + ni * 16 + col);
#pragma unroll
        for (int r = 0; r < 4; ++r)
          P[base + (size_t)r * 512] = (f16)acc[w][mi][ni][r];
      }
  }
}

// ---------------- kernel 4: recurrent scan ----------------
// One thread per (batch, hidden) chain; group-of-8 double-buffered prefetch.
__global__ void __launch_bounds__(256) brc_scan(
    const f16* __restrict__ Pr, const f16* __restrict__ Pz, const f16* __restrict__ Ph,
    const float* __restrict__ h0, const float* __restrict__ mr, const float* __restrict__ mz,
    const float* __restrict__ br, const float* __restrict__ bz,
    float* __restrict__ out, int b0) {
  int gid = blockIdx.x * 256 + threadIdx.x;   // 0 .. bc*512-1
  int bb = gid >> 9;
  int i = gid & 511;
  float h = h0[((size_t)(b0 + bb) << 9) + i];
  float mri = mr[i], mzi = mz[i], bri = br[i], bzi = bz[i];
  size_t pbase = ((size_t)bb << 18) + i;                 // bb*T*H + i
  const f16* prp = Pr + pbase;
  const f16* pzp = Pz + pbase;
  const f16* php = Ph + pbase;
  float* op = out + (((size_t)(b0 + bb)) << 18) + i;

  f16 Ar[8], Az[8], Ah[8], Cr[8], Cz[8], Ch[8];

#define LOADG(dr, dz, dh, g)                                            \
  do {                                                                  \
    size_t o_ = ((size_t)(g) << 12);                                    \
    _Pragma("unroll") for (int j = 0; j < 8; ++j) {                     \
      dr[j] = prp[o_ + (size_t)j * 512];                                \
      dz[j] = pzp[o_ + (size_t)j * 512];                                \
      dh[j] = php[o_ + (size_t)j * 512];                                \
    }                                                                   \
  } while (0)

#define STEP8(dr, dz, dh, g)                                            \
  do {                                                                  \
    size_t o_ = ((size_t)(g) << 12);                                    \
    _Pragma("unroll") for (int j = 0; j < 8; ++j) {                     \
      float prf = (float)dr[j] + bri;                                   \
      float pzf = (float)dz[j] + bzi;                                   \
      float phf = (float)dh[j];                                         \
      float r = fast_tanh(fmaf(h, mri, prf)) + 1.0f;                    \
      float z = fast_sigmoid(fmaf(h, mzi, pzf));                        \
      float cand = fast_tanh(fmaf(r, h, phf));                          \
      h = z * h + (1.0f - z) * cand;                                    \
      op[o_ + (size_t)j * 512] = h;                                     \
    }                                                                   \
  } while (0)

  LOADG(Ar, Az, Ah, 0);
  for (int g = 0; g < 64; g += 2) {
    LOADG(Cr, Cz, Ch, g + 1);
    STEP8(Ar, Az, Ah, g);
    if (g + 2 < 64) LOADG(Ar, Az, Ah, g + 2);
    STEP8(Cr, Cz, Ch, g + 1);
  }
#undef LOADG
#undef STEP8
}

// ---------------- launch ----------------
extern "C" void kernel_launch(void* const* d_in, const int* in_sizes, int n_in,
                              void* d_out, int out_size, void* d_ws, size_t ws_size,
                              hipStream_t stream) {
  const float* x  = (const float*)d_in[0];
  const float* h0 = (const float*)d_in[1];
  const float* kr = (const float*)d_in[2];
  const float* kz = (const float*)d_in[3];
  const float* kh = (const float*)d_in[4];
  const float* mr = (const float*)d_in[5];
  const float* mz = (const float*)d_in[6];
  const float* br = (const float*)d_in[7];
  const float* bz = (const float*)d_in[8];
  float* out = (float*)d_out;

  f16* ws = (f16*)d_ws;
  f16* Wtr = ws;
  f16* Wtz = ws + 131072;
  f16* Wth = ws + 262144;

  // per-batch ws need (bytes): x_f16 = 262144, pr/pz/ph = 3*524288 -> 1835008
  size_t avail = ws_size > 786432 ? ws_size - 786432 : 0;
  int Bc = (int)(avail / 1835008ull);
  if (Bc < 1) Bc = 1;
  if (Bc > B_TOT) Bc = B_TOT;

  cvt_w<<<1536, 256, 0, stream>>>(kr, kz, kh, ws);

  for (int b0 = 0; b0 < B_TOT; b0 += Bc) {
    int bc = (Bc < B_TOT - b0) ? Bc : (B_TOT - b0);
    f16* Xf = ws + 393216;
    f16* Pr = Xf + (size_t)bc * 131072;
    f16* Pz = Pr + (size_t)bc * 262144;
    f16* Ph = Pz + (size_t)bc * 262144;

    cvt_x<<<bc * 128, 256, 0, stream>>>(
        (const float4*)(x + (size_t)b0 * 131072), (f16x4*)Xf);
    brc_gemm3<<<bc * 32, 256, 0, stream>>>(Xf, Wtr, Wtz, Wth, Pr, Pz, Ph, bc * 4);
    brc_scan<<<bc * 2, 256, 0, stream>>>(Pr, Pz, Ph, h0, mr, mz, br, bz, out, b0);
  }
}